// Round 15
// baseline (278.461 us; speedup 1.0000x reference)
//
#include <hip/hip_runtime.h>
#include <stdint.h>

#define H_DIM 1024
#define I_DIM 4096
#define E_NUM 8
#define CAP   1024

typedef __attribute__((ext_vector_type(8))) short bf16x8;
typedef __attribute__((ext_vector_type(4))) float f32x4;

#define AS1 __attribute__((address_space(1)))
#define AS3 __attribute__((address_space(3)))

__device__ __forceinline__ unsigned short f2bf(float f){
  union { float f; uint32_t u; } v; v.f = f;
  uint32_t u = v.u;
  uint32_t r = (u + 0x7FFFu + ((u >> 16) & 1u)) >> 16;
  return (unsigned short)r;
}

// ---- fused prep ----
// [0,1024)      zero out (32 MB)
// [1024,2048)   router softmax + x->bf16 (first CAP tokens)
// [2048,10240)  W1 (E,H,I) -> W1^T (E,I,H) bf16
// [10240,18432) W2 flat (E*I x H) -> W2^T (H x E*I) bf16   (big-ws launch only)
// All parts write disjoint buffers; no cross-part ordering needed.
__global__ __launch_bounds__(256) void prep_kernel(
    const float* __restrict__ x, const float* __restrict__ rw_w,
    const float* __restrict__ rb, const float* __restrict__ w1,
    const float* __restrict__ w2,
    float* __restrict__ out, int n4,
    unsigned short* __restrict__ xb, float* __restrict__ rwout,
    unsigned short* __restrict__ wt, unsigned short* __restrict__ w2t)
{
  __shared__ float smem[64][65];
  int bid = blockIdx.x;
  int t   = threadIdx.x;

  if (bid < 1024){
    float4 z; z.x=0.f; z.y=0.f; z.z=0.f; z.w=0.f;
    float4* p = (float4*)out;
    for (int i = bid*256 + t; i < n4; i += 1024*256) p[i] = z;
    return;
  }
  if (bid < 2048){
    int c = bid - 1024;
    const float* xr = x + (size_t)c*H_DIM;
    float4 xv = *(const float4*)(xr + t*4);
    ushort4 xo;
    xo.x = f2bf(xv.x); xo.y = f2bf(xv.y); xo.z = f2bf(xv.z); xo.w = f2bf(xv.w);
    *(ushort4*)(xb + (size_t)c*H_DIM + t*4) = xo;
    float acc[E_NUM];
    #pragma unroll
    for (int e=0;e<E_NUM;e++){
      float4 wv = *(const float4*)(rw_w + e*H_DIM + t*4);
      acc[e] = xv.x*wv.x + xv.y*wv.y + xv.z*wv.z + xv.w*wv.w;
    }
    float (*part)[E_NUM] = (float (*)[E_NUM])smem;
    #pragma unroll
    for (int e=0;e<E_NUM;e++) part[t][e]=acc[e];
    __syncthreads();
    for (int s=128; s>0; s>>=1){
      if (t<s){
        #pragma unroll
        for (int e=0;e<E_NUM;e++) part[t][e]+=part[t+s][e];
      }
      __syncthreads();
    }
    if (t==0){
      float l[E_NUM], mx=-1e30f;
      #pragma unroll
      for (int e=0;e<E_NUM;e++){ l[e]=part[0][e]+rb[e]; mx=fmaxf(mx,l[e]); }
      float s=0.f;
      #pragma unroll
      for (int e=0;e<E_NUM;e++){ l[e]=expf(l[e]-mx); s+=l[e]; }
      float inv = 1.f/s;
      #pragma unroll
      for (int e=0;e<E_NUM;e++) rwout[c*E_NUM+e] = l[e]*inv;
    }
    return;
  }
  if (bid < 10240){
    // W1 (E,H,I) -> W1^T per expert (I x H) bf16, 64x64 tiles
    int idx = bid - 2048;
    int e   = idx >> 10;
    int rem = idx & 1023;
    int by  = rem >> 6, bx = rem & 63;
    const float* src = w1 + (size_t)e*H_DIM*I_DIM;
    unsigned short* dst = wt + (size_t)e*I_DIM*H_DIM;
    int c0 = bx*64, r0 = by*64;
    int tx = t & 15, ty = t >> 4;
    #pragma unroll
    for (int p=0;p<4;p++){
      int r = ty + p*16;
      float4 v = *(const float4*)(src + (size_t)(r0+r)*I_DIM + c0 + tx*4);
      smem[r][tx*4+0]=v.x; smem[r][tx*4+1]=v.y; smem[r][tx*4+2]=v.z; smem[r][tx*4+3]=v.w;
    }
    __syncthreads();
    #pragma unroll
    for (int p=0;p<4;p++){
      int c = ty + p*16;
      ushort4 o;
      o.x = f2bf(smem[tx*4+0][c]);
      o.y = f2bf(smem[tx*4+1][c]);
      o.z = f2bf(smem[tx*4+2][c]);
      o.w = f2bf(smem[tx*4+3][c]);
      *(ushort4*)(dst + (size_t)(c0+c)*H_DIM + r0 + tx*4) = o;
    }
    return;
  }
  // W2 flat (E*I=32768 x H=1024) -> W2^T (1024 x 32768) bf16, 64x64 tiles.
  // Only launched in the big-ws path (grid 18432); w2t distinct from wt.
  {
    int idx = bid - 10240;               // ry*16 + cx;  ry<512, cx<16
    int ry  = idx >> 4, cx = idx & 15;
    int r0  = ry*64, c0 = cx*64;
    int tx = t & 15, ty = t >> 4;
    #pragma unroll
    for (int p=0;p<4;p++){
      int r = ty + p*16;
      float4 v = *(const float4*)(w2 + (size_t)(r0+r)*H_DIM + c0 + tx*4);
      smem[r][tx*4+0]=v.x; smem[r][tx*4+1]=v.y; smem[r][tx*4+2]=v.z; smem[r][tx*4+3]=v.w;
    }
    __syncthreads();
    #pragma unroll
    for (int p=0;p<4;p++){
      int c = ty + p*16;
      ushort4 o;
      o.x = f2bf(smem[tx*4+0][c]);
      o.y = f2bf(smem[tx*4+1][c]);
      o.z = f2bf(smem[tx*4+2][c]);
      o.w = f2bf(smem[tx*4+3][c]);
      *(ushort4*)(w2t + (size_t)(c0+c)*(E_NUM*I_DIM) + r0 + tx*4) = o;
    }
  }
}

// ------- standalone fp32 -> bf16 transpose (fallback path only) -------
__global__ __launch_bounds__(256) void transpose_cvt64(
    const float* __restrict__ src, unsigned short* __restrict__ dst,
    int R, int C, long srcZ, long dstZ)
{
  src += (size_t)blockIdx.z * srcZ;
  dst += (size_t)blockIdx.z * dstZ;
  __shared__ float tile[64][65];
  int c0 = blockIdx.x*64, r0 = blockIdx.y*64;
  int t  = threadIdx.x;
  int tx = t & 15, ty = t >> 4;
  #pragma unroll
  for (int p=0;p<4;p++){
    int r = ty + p*16;
    float4 v = *(const float4*)(src + (size_t)(r0+r)*C + c0 + tx*4);
    tile[r][tx*4+0]=v.x; tile[r][tx*4+1]=v.y; tile[r][tx*4+2]=v.z; tile[r][tx*4+3]=v.w;
  }
  __syncthreads();
  #pragma unroll
  for (int p=0;p<4;p++){
    int c = ty + p*16;
    ushort4 o;
    o.x = f2bf(tile[tx*4+0][c]);
    o.y = f2bf(tile[tx*4+1][c]);
    o.z = f2bf(tile[tx*4+2][c]);
    o.w = f2bf(tile[tx*4+3][c]);
    *(ushort4*)(dst + (size_t)(c0+c)*R + r0 + tx*4) = o;
  }
}

// ---- 128x256 bf16 GEMM, B N-major, BK=64, SINGLE 48KB LDS buffer ----
// Best-measured configuration (R11/R13/R14: 247-248 us, GEMMs ~105 us each,
// 655 TF = the documented 2-phase plain-HIP plateau at this shape):
// 8 waves 2Mx4N, wave out 64x64 (acc 64 AGPR + ~60 VGPR under the 128 cap),
// launch_bounds(512,4) -> 2 blocks/CU; cross-block wave overlap covers the
// __syncthreads vmcnt drains (m114/m97 mechanism). Plain 2-barrier loop.
// Read swizzle = measured-zero-conflict pattern: 128B rows,
// slot = (kk*4+lq) ^ (lrow&7); staging source pre-swizzled, LDS dest linear.
// MODE 0: relu*rw -> bf16 inter.  MODE 1: atomicAdd fp32.
template<int MODE>
__global__ __launch_bounds__(512, 4) void gemm_s(
    const unsigned short* __restrict__ A, int lda, long aZ,
    const unsigned short* __restrict__ B, int ldb, long bZ,
    int NS, int tilesPerZ,
    const float* __restrict__ rw,
    unsigned short* __restrict__ outInter,
    float* __restrict__ outAdd)
{
  __shared__ unsigned short As[128*64];   // 16 KB
  __shared__ unsigned short Bs[256*64];   // 32 KB

  int nwg = gridDim.x;
  int id  = blockIdx.x;
  int swz = (id & 7)*(nwg >> 3) + (id >> 3);
  int z   = swz / tilesPerZ;
  int rr_ = swz - z*tilesPerZ;
  int mt  = rr_ & 7, nt = rr_ >> 3;
  int m0  = mt*128, n0 = nt*256;

  const unsigned short* Ab = A + (size_t)z*aZ + (size_t)m0*lda;
  const unsigned short* Bb = B + (size_t)z*bZ + (size_t)n0*ldb;

  int tid  = threadIdx.x;
  int w    = tid >> 6, l = tid & 63;
  int wr   = w >> 2,  wc = w & 3;       // wave grid 2M x 4N, wave out 64x64
  int lrow = l & 15,  lq = l >> 4;
  int r7   = lrow & 7;

  int srow = l >> 3;
  int sg   = ((l & 7) ^ ((l >> 3) & 7)) * 8;

  f32x4 acc[4][4];
  #pragma unroll
  for (int i=0;i<4;i++)
    #pragma unroll
    for (int j=0;j<4;j++)
      acc[i][j] = (f32x4){0.f,0.f,0.f,0.f};

  for (int s=0; s<NS; ++s){
    int kt = s*64;
    #pragma unroll
    for (int i=0;i<2;i++){
      int rbase = w*16 + i*8;
      __builtin_amdgcn_global_load_lds(
        (const AS1 void*)(Ab + (size_t)(rbase + srow)*lda + kt + sg),
        (AS3 void*)((char*)As + rbase*128), 16, 0, 0);
    }
    #pragma unroll
    for (int i=0;i<4;i++){
      int rbase = w*32 + i*8;
      __builtin_amdgcn_global_load_lds(
        (const AS1 void*)(Bb + (size_t)(rbase + srow)*ldb + kt + sg),
        (AS3 void*)((char*)Bs + rbase*128), 16, 0, 0);
    }
    __syncthreads();

    #pragma unroll
    for (int kk=0;kk<2;kk++){
      bf16x8 af[4], bfr[4];
      int slot = ((kk*4 + lq) ^ r7) << 4;
      #pragma unroll
      for (int f=0;f<4;f++)
        af[f]  = *(const bf16x8*)((const char*)As + (wr*64 + f*16 + lrow)*128 + slot);
      #pragma unroll
      for (int f=0;f<4;f++)
        bfr[f] = *(const bf16x8*)((const char*)Bs + (wc*64 + f*16 + lrow)*128 + slot);
      #pragma unroll
      for (int fm=0;fm<4;fm++)
        #pragma unroll
        for (int fn=0;fn<4;fn++)
          acc[fm][fn] = __builtin_amdgcn_mfma_f32_16x16x32_bf16(af[fm], bfr[fn], acc[fm][fn], 0, 0, 0);
    }

    __syncthreads();
  }

  #pragma unroll
  for (int fm=0;fm<4;fm++){
    #pragma unroll
    for (int fn=0;fn<4;fn++){
      #pragma unroll
      for (int rg=0;rg<4;rg++){
        int gm = m0 + wr*64 + fm*16 + lq*4 + rg;
        int gn = n0 + wc*64 + fn*16 + lrow;
        float v = acc[fm][fn][rg];
        if (MODE==0){
          v = fmaxf(v, 0.f) * rw[gm*E_NUM + z];
          outInter[(size_t)gm*(E_NUM*I_DIM) + (size_t)z*I_DIM + gn] = f2bf(v);
        } else {
          atomicAdd(&outAdd[(size_t)gm*H_DIM + gn], v);
        }
      }
    }
  }
}

extern "C" void kernel_launch(void* const* d_in, const int* in_sizes, int n_in,
                              void* d_out, int out_size, void* d_ws, size_t ws_size,
                              hipStream_t stream)
{
  const float* x   = (const float*)d_in[0];
  const float* rww = (const float*)d_in[1];
  const float* rwb = (const float*)d_in[2];
  const float* w1  = (const float*)d_in[3];  // (E, H, I)
  const float* w2  = (const float*)d_in[4];  // (E, I, H)
  float* out = (float*)d_out;

  char* ws = (char*)d_ws;
  float*          rwout = (float*)(ws);                         // 32 KB
  unsigned short* xb    = (unsigned short*)(ws + (1u<<16));     // 2 MB  @64KB
  unsigned short* inter = (unsigned short*)(ws + (4ull<<20));   // 64 MB @4MB
  unsigned short* wt    = (unsigned short*)(ws + (68ull<<20));  // 64 MB @68MB
  unsigned short* w2t   = (unsigned short*)(ws + (132ull<<20)); // 64 MB @132MB
  const size_t needed     = 132ull<<20;
  const size_t needed_big = 196ull<<20;   // proven available by R12's fused run

  if (ws_size < needed){
    prep_kernel<<<1024, 256, 0, stream>>>(x, rww, rwb, w1, w2, out, out_size/4,
                                          xb, rwout, wt, wt);
    return;
  }

  if (ws_size >= needed_big){
    // prep: zero | router | W1^T | W2^T (to w2t, distinct buffer) — 1 dispatch
    prep_kernel<<<18432, 256, 0, stream>>>(x, rww, rwb, w1, w2, out, out_size/4,
                                           xb, rwout, wt, w2t);

    // GEMM1: grid 1024 = (8 mtiles x 16 ntiles) x 8 experts; K=1024 -> NS=16
    gemm_s<0><<<1024, 512, 0, stream>>>(
        xb, H_DIM, 0L,
        wt, H_DIM, (long)I_DIM*H_DIM,
        16, 128, rwout, inter, nullptr);

    // GEMM2: grid 512 = (8 mtiles x 4 ntiles) x 16 z; NS=32; reads w2t
    gemm_s<1><<<512, 512, 0, stream>>>(
        inter, E_NUM*I_DIM, 2048L,
        w2t,   E_NUM*I_DIM, 2048L,
        32, 32, nullptr, nullptr, out);
  } else {
    // fallback: R14 exact sequence (prep w/o W2^T, serial transpose into wt)
    prep_kernel<<<10240, 256, 0, stream>>>(x, rww, rwb, w1, w2, out, out_size/4,
                                           xb, rwout, wt, wt);
    gemm_s<0><<<1024, 512, 0, stream>>>(
        xb, H_DIM, 0L,
        wt, H_DIM, (long)I_DIM*H_DIM,
        16, 128, rwout, inter, nullptr);
    transpose_cvt64<<<dim3(H_DIM/64, (E_NUM*I_DIM)/64, 1), 256, 0, stream>>>(
        w2, wt, E_NUM*I_DIM, H_DIM, 0L, 0L);
    gemm_s<1><<<512, 512, 0, stream>>>(
        inter, E_NUM*I_DIM, 2048L,
        wt,    E_NUM*I_DIM, 2048L,
        32, 32, nullptr, nullptr, out);
  }
}

// Round 16
// 245.944 us; speedup vs baseline: 1.1322x; 1.1322x over previous
//
#include <hip/hip_runtime.h>
#include <stdint.h>

#define H_DIM 1024
#define I_DIM 4096
#define E_NUM 8
#define CAP   1024

typedef __attribute__((ext_vector_type(8))) short bf16x8;
typedef __attribute__((ext_vector_type(4))) float f32x4;

#define AS1 __attribute__((address_space(1)))
#define AS3 __attribute__((address_space(3)))

__device__ __forceinline__ unsigned short f2bf(float f){
  union { float f; uint32_t u; } v; v.f = f;
  uint32_t u = v.u;
  uint32_t r = (u + 0x7FFFu + ((u >> 16) & 1u)) >> 16;
  return (unsigned short)r;
}

// ---- fused prep: [0,1024) zero out | [1024,2048) router | [2048,10240) W1^T ----
// All three parts write disjoint buffers; no cross-part ordering needed.
// (W2^T deliberately NOT fused: R15 measured the fusion at +31 us — prep BW
// collapses to 2.5 TB/s and the dirty w2t lines slow both GEMMs.)
__global__ __launch_bounds__(256) void prep_kernel(
    const float* __restrict__ x, const float* __restrict__ rw_w,
    const float* __restrict__ rb, const float* __restrict__ w1,
    float* __restrict__ out, int n4,
    unsigned short* __restrict__ xb, float* __restrict__ rwout,
    unsigned short* __restrict__ wt)
{
  __shared__ float smem[64][65];
  int bid = blockIdx.x;
  int t   = threadIdx.x;

  if (bid < 1024){
    float4 z; z.x=0.f; z.y=0.f; z.z=0.f; z.w=0.f;
    float4* p = (float4*)out;
    for (int i = bid*256 + t; i < n4; i += 1024*256) p[i] = z;
    return;
  }
  if (bid < 2048){
    int c = bid - 1024;
    const float* xr = x + (size_t)c*H_DIM;
    float4 xv = *(const float4*)(xr + t*4);
    ushort4 xo;
    xo.x = f2bf(xv.x); xo.y = f2bf(xv.y); xo.z = f2bf(xv.z); xo.w = f2bf(xv.w);
    *(ushort4*)(xb + (size_t)c*H_DIM + t*4) = xo;
    float acc[E_NUM];
    #pragma unroll
    for (int e=0;e<E_NUM;e++){
      float4 wv = *(const float4*)(rw_w + e*H_DIM + t*4);
      acc[e] = xv.x*wv.x + xv.y*wv.y + xv.z*wv.z + xv.w*wv.w;
    }
    float (*part)[E_NUM] = (float (*)[E_NUM])smem;
    #pragma unroll
    for (int e=0;e<E_NUM;e++) part[t][e]=acc[e];
    __syncthreads();
    for (int s=128; s>0; s>>=1){
      if (t<s){
        #pragma unroll
        for (int e=0;e<E_NUM;e++) part[t][e]+=part[t+s][e];
      }
      __syncthreads();
    }
    if (t==0){
      float l[E_NUM], mx=-1e30f;
      #pragma unroll
      for (int e=0;e<E_NUM;e++){ l[e]=part[0][e]+rb[e]; mx=fmaxf(mx,l[e]); }
      float s=0.f;
      #pragma unroll
      for (int e=0;e<E_NUM;e++){ l[e]=expf(l[e]-mx); s+=l[e]; }
      float inv = 1.f/s;
      #pragma unroll
      for (int e=0;e<E_NUM;e++) rwout[c*E_NUM+e] = l[e]*inv;
    }
    return;
  }
  // W1 (E,H,I) -> W1^T per expert (I x H) bf16, 64x64 tiles
  int idx = bid - 2048;
  int e   = idx >> 10;
  int rem = idx & 1023;
  int by  = rem >> 6, bx = rem & 63;
  const float* src = w1 + (size_t)e*H_DIM*I_DIM;
  unsigned short* dst = wt + (size_t)e*I_DIM*H_DIM;
  int c0 = bx*64, r0 = by*64;
  int tx = t & 15, ty = t >> 4;
  #pragma unroll
  for (int p=0;p<4;p++){
    int r = ty + p*16;
    float4 v = *(const float4*)(src + (size_t)(r0+r)*I_DIM + c0 + tx*4);
    smem[r][tx*4+0]=v.x; smem[r][tx*4+1]=v.y; smem[r][tx*4+2]=v.z; smem[r][tx*4+3]=v.w;
  }
  __syncthreads();
  #pragma unroll
  for (int p=0;p<4;p++){
    int c = ty + p*16;
    ushort4 o;
    o.x = f2bf(smem[tx*4+0][c]);
    o.y = f2bf(smem[tx*4+1][c]);
    o.z = f2bf(smem[tx*4+2][c]);
    o.w = f2bf(smem[tx*4+3][c]);
    *(ushort4*)(dst + (size_t)(c0+c)*H_DIM + r0 + tx*4) = o;
  }
}

// ------- fp32 -> bf16 transpose, 64x64 tile, float4 loads / ushort4 stores -------
__global__ __launch_bounds__(256) void transpose_cvt64(
    const float* __restrict__ src, unsigned short* __restrict__ dst,
    int R, int C, long srcZ, long dstZ)
{
  src += (size_t)blockIdx.z * srcZ;
  dst += (size_t)blockIdx.z * dstZ;
  __shared__ float tile[64][65];
  int c0 = blockIdx.x*64, r0 = blockIdx.y*64;
  int t  = threadIdx.x;
  int tx = t & 15, ty = t >> 4;
  #pragma unroll
  for (int p=0;p<4;p++){
    int r = ty + p*16;
    float4 v = *(const float4*)(src + (size_t)(r0+r)*C + c0 + tx*4);
    tile[r][tx*4+0]=v.x; tile[r][tx*4+1]=v.y; tile[r][tx*4+2]=v.z; tile[r][tx*4+3]=v.w;
  }
  __syncthreads();
  #pragma unroll
  for (int p=0;p<4;p++){
    int c = ty + p*16;
    ushort4 o;
    o.x = f2bf(tile[tx*4+0][c]);
    o.y = f2bf(tile[tx*4+1][c]);
    o.z = f2bf(tile[tx*4+2][c]);
    o.w = f2bf(tile[tx*4+3][c]);
    *(ushort4*)(dst + (size_t)(c0+c)*R + r0 + tx*4) = o;
  }
}

// ---- 128x256 bf16 GEMM, B N-major, BK=64, SINGLE 48KB LDS buffer ----
// Final configuration (best measured: 247.4/247.5/248.1 us across 3 runs):
// 8 waves 2Mx4N, wave out 64x64 (acc 64 AGPR), launch_bounds(512,4) ->
// 2 blocks/CU (4 waves/SIMD): cross-block wave overlap covers the
// __syncthreads vmcnt drains (m114/m97 mechanism). Plain 2-barrier loop;
// no setprio (null on this lockstep structure, R14 A/B).
// Read swizzle = measured-zero-conflict pattern: 128B rows,
// slot = (kk*4+lq) ^ (lrow&7); staging source pre-swizzled, LDS dest linear.
// MODE 0: relu*rw -> bf16 inter.  MODE 1: atomicAdd fp32.
template<int MODE>
__global__ __launch_bounds__(512, 4) void gemm_s(
    const unsigned short* __restrict__ A, int lda, long aZ,
    const unsigned short* __restrict__ B, int ldb, long bZ,
    int NS, int tilesPerZ,
    const float* __restrict__ rw,
    unsigned short* __restrict__ outInter,
    float* __restrict__ outAdd)
{
  __shared__ unsigned short As[128*64];   // 16 KB
  __shared__ unsigned short Bs[256*64];   // 32 KB

  int nwg = gridDim.x;
  int id  = blockIdx.x;
  int swz = (id & 7)*(nwg >> 3) + (id >> 3);
  int z   = swz / tilesPerZ;
  int rr_ = swz - z*tilesPerZ;
  int mt  = rr_ & 7, nt = rr_ >> 3;
  int m0  = mt*128, n0 = nt*256;

  const unsigned short* Ab = A + (size_t)z*aZ + (size_t)m0*lda;
  const unsigned short* Bb = B + (size_t)z*bZ + (size_t)n0*ldb;

  int tid  = threadIdx.x;
  int w    = tid >> 6, l = tid & 63;
  int wr   = w >> 2,  wc = w & 3;       // wave grid 2M x 4N, wave out 64x64
  int lrow = l & 15,  lq = l >> 4;
  int r7   = lrow & 7;

  int srow = l >> 3;
  int sg   = ((l & 7) ^ ((l >> 3) & 7)) * 8;

  f32x4 acc[4][4];
  #pragma unroll
  for (int i=0;i<4;i++)
    #pragma unroll
    for (int j=0;j<4;j++)
      acc[i][j] = (f32x4){0.f,0.f,0.f,0.f};

  for (int s=0; s<NS; ++s){
    int kt = s*64;
    #pragma unroll
    for (int i=0;i<2;i++){
      int rbase = w*16 + i*8;
      __builtin_amdgcn_global_load_lds(
        (const AS1 void*)(Ab + (size_t)(rbase + srow)*lda + kt + sg),
        (AS3 void*)((char*)As + rbase*128), 16, 0, 0);
    }
    #pragma unroll
    for (int i=0;i<4;i++){
      int rbase = w*32 + i*8;
      __builtin_amdgcn_global_load_lds(
        (const AS1 void*)(Bb + (size_t)(rbase + srow)*ldb + kt + sg),
        (AS3 void*)((char*)Bs + rbase*128), 16, 0, 0);
    }
    __syncthreads();

    #pragma unroll
    for (int kk=0;kk<2;kk++){
      bf16x8 af[4], bfr[4];
      int slot = ((kk*4 + lq) ^ r7) << 4;
      #pragma unroll
      for (int f=0;f<4;f++)
        af[f]  = *(const bf16x8*)((const char*)As + (wr*64 + f*16 + lrow)*128 + slot);
      #pragma unroll
      for (int f=0;f<4;f++)
        bfr[f] = *(const bf16x8*)((const char*)Bs + (wc*64 + f*16 + lrow)*128 + slot);
      #pragma unroll
      for (int fm=0;fm<4;fm++)
        #pragma unroll
        for (int fn=0;fn<4;fn++)
          acc[fm][fn] = __builtin_amdgcn_mfma_f32_16x16x32_bf16(af[fm], bfr[fn], acc[fm][fn], 0, 0, 0);
    }

    __syncthreads();
  }

  #pragma unroll
  for (int fm=0;fm<4;fm++){
    #pragma unroll
    for (int fn=0;fn<4;fn++){
      #pragma unroll
      for (int rg=0;rg<4;rg++){
        int gm = m0 + wr*64 + fm*16 + lq*4 + rg;
        int gn = n0 + wc*64 + fn*16 + lrow;
        float v = acc[fm][fn][rg];
        if (MODE==0){
          v = fmaxf(v, 0.f) * rw[gm*E_NUM + z];
          outInter[(size_t)gm*(E_NUM*I_DIM) + (size_t)z*I_DIM + gn] = f2bf(v);
        } else {
          atomicAdd(&outAdd[(size_t)gm*H_DIM + gn], v);
        }
      }
    }
  }
}

extern "C" void kernel_launch(void* const* d_in, const int* in_sizes, int n_in,
                              void* d_out, int out_size, void* d_ws, size_t ws_size,
                              hipStream_t stream)
{
  const float* x   = (const float*)d_in[0];
  const float* rww = (const float*)d_in[1];
  const float* rwb = (const float*)d_in[2];
  const float* w1  = (const float*)d_in[3];  // (E, H, I)
  const float* w2  = (const float*)d_in[4];  // (E, I, H)
  float* out = (float*)d_out;

  char* ws = (char*)d_ws;
  float*          rwout = (float*)(ws);                         // 32 KB
  unsigned short* xb    = (unsigned short*)(ws + (1u<<16));     // 2 MB  @64KB
  unsigned short* inter = (unsigned short*)(ws + (4ull<<20));   // 64 MB @4MB
  unsigned short* wt    = (unsigned short*)(ws + (68ull<<20));  // 64 MB @68MB
  const size_t needed = 132ull<<20;

  if (ws_size < needed){
    prep_kernel<<<1024, 256, 0, stream>>>(x, rww, rwb, w1, out, out_size/4,
                                          xb, rwout, wt);
    return;
  }

  // prep: zero(out) | router(xb,rwout) | W1^T(wt) in one dispatch
  prep_kernel<<<10240, 256, 0, stream>>>(x, rww, rwb, w1, out, out_size/4,
                                         xb, rwout, wt);

  // GEMM1: inter[c, e*I+n] = bf16( relu( xb @ W1_e^T ) * rw[c,e] )
  // grid 1024 = (8 mtiles x 16 ntiles) x 8 experts; K=1024 -> NS=16
  gemm_s<0><<<1024, 512, 0, stream>>>(
      xb, H_DIM, 0L,
      wt, H_DIM, (long)I_DIM*H_DIM,
      16, 128, rwout, inter, nullptr);

  // W2 flat (E*I x H) -> W2^T (H x E*I) bf16  (reuses wt after GEMM1)
  transpose_cvt64<<<dim3(H_DIM/64, (E_NUM*I_DIM)/64, 1), 256, 0, stream>>>(
      w2, wt, E_NUM*I_DIM, H_DIM, 0L, 0L);

  // GEMM2: out[c,h] += inter[c,:] @ W2^T[h,:]; split-K z=16 slices of 2048 -> NS=32
  // grid 512 = (8 mtiles x 4 ntiles) x 16 z
  gemm_s<1><<<512, 512, 0, stream>>>(
      inter, E_NUM*I_DIM, 2048L,
      wt,    E_NUM*I_DIM, 2048L,
      32, 32, nullptr, nullptr, out);
}